// Round 11
// baseline (424.863 us; speedup 1.0000x reference)
//
#include <hip/hip_runtime.h>

#define D 64
#define BLK 256
#define BLK_SC 1024         // big blocks for the latency-bound bucket passes
#define BSH 8               // bucket = 256 rows
#define BROWS 256
#define NBMAX 1024
#define ETILE 8192

typedef unsigned int uint;
typedef float floatx2 __attribute__((ext_vector_type(2)));

static inline int cdiv(long a, long b) { return (int)((a + b - 1) / b); }

// ---------------- fp8 e4m3 helpers (HW converts on gfx950, OCP format) ----------------
#if defined(__has_builtin) && __has_builtin(__builtin_amdgcn_cvt_pk_f32_fp8) && __has_builtin(__builtin_amdgcn_cvt_pk_fp8_f32)
__device__ __forceinline__ float4 fp8x4_dec(uint u) {
    floatx2 lo = __builtin_amdgcn_cvt_pk_f32_fp8((int)u, false);
    floatx2 hi = __builtin_amdgcn_cvt_pk_f32_fp8((int)u, true);
    float4 r; r.x = lo[0]; r.y = lo[1]; r.z = hi[0]; r.w = hi[1];
    return r;
}
__device__ __forceinline__ uint fp8x4_enc(float a, float b, float c, float d) {
    int v = __builtin_amdgcn_cvt_pk_fp8_f32(a, b, 0, false);
    v = __builtin_amdgcn_cvt_pk_fp8_f32(c, d, v, true);
    return (uint)v;
}
#else
__device__ __forceinline__ float fp8_dec1(uint b) {
    uint s = (b >> 7) & 1u, e = (b >> 3) & 15u, m = b & 7u;
    float v = e ? __uint_as_float(((e + 120u) << 23) | (m << 20))
                : (float)m * 0.001953125f;
    return s ? -v : v;
}
__device__ __forceinline__ uint fp8_enc1(float f) {
    uint u = __float_as_uint(f);
    uint s = (u >> 31) << 7;
    float a = fabsf(f);
    if (a >= 448.0f) return s | 0x7Eu;
    if (a < 0.001953125f) {
        uint m = (uint)(a * 512.0f + 0.5f);
        return s | (m > 7u ? 7u : m);
    }
    int e = (int)((u >> 23) & 0xFF) - 127;
    uint mant = (u >> 20) & 7u;
    uint rest = u & 0xFFFFFu;
    if (rest > 0x80000u || (rest == 0x80000u && (mant & 1u))) {
        mant++; if (mant == 8u) { mant = 0u; e++; }
    }
    if (e > 8) return s | 0x7Eu;
    if (e < -6) { uint m = (uint)(a * 512.0f + 0.5f); return s | (m > 7u ? 7u : m); }
    return s | ((uint)(e + 7) << 3) | mant;
}
__device__ __forceinline__ float4 fp8x4_dec(uint u) {
    float4 r;
    r.x = fp8_dec1(u & 0xFF); r.y = fp8_dec1((u >> 8) & 0xFF);
    r.z = fp8_dec1((u >> 16) & 0xFF); r.w = fp8_dec1(u >> 24);
    return r;
}
__device__ __forceinline__ uint fp8x4_enc(float a, float b, float c, float d) {
    return fp8_enc1(a) | (fp8_enc1(b) << 8) | (fp8_enc1(c) << 16) | (fp8_enc1(d) << 24);
}
#endif

// ---------------- bucketed CSR build ----------------
__global__ void k_zb(int* __restrict__ a, int* __restrict__ b) {
    int i = blockIdx.x * BLK + threadIdx.x;
    if (i < NBMAX) { a[i] = 0; b[i] = 0; }
}

// P1 fused: bucket histogram for BOTH graphs; blockIdx < gTP -> positive. 2-way unrolled.
__global__ void kb_count2(const int* __restrict__ row_p, int* __restrict__ bcntp, int ep,
                          const int* __restrict__ row_n, int* __restrict__ bcntn, int en,
                          int gTP, int nb) {
    const int posblk = (int)blockIdx.x < gTP;
    const int* row = posblk ? row_p : row_n;
    int* bcnt      = posblk ? bcntp : bcntn;
    int  e         = posblk ? ep : en;
    int  tile      = posblk ? (int)blockIdx.x : (int)blockIdx.x - gTP;
    __shared__ int hist[NBMAX];
    int t = threadIdx.x;
    for (int b = t; b < nb; b += BLK_SC) hist[b] = 0;
    __syncthreads();
    int bs = tile * ETILE;
    int be = bs + ETILE; if (be > e) be = e;
    int i = bs + t;
    for (; i + BLK_SC < be; i += 2 * BLK_SC) {
        int r0 = row[i], r1 = row[i + BLK_SC];
        atomicAdd(&hist[r0 >> BSH], 1);
        atomicAdd(&hist[r1 >> BSH], 1);
    }
    if (i < be) atomicAdd(&hist[row[i] >> BSH], 1);
    __syncthreads();
    for (int b = t; b < nb; b += BLK_SC) {
        int c = hist[b];
        if (c) atomicAdd(&bcnt[b], c);
    }
}

__global__ void kb_scan(const int* __restrict__ bcntp, int* __restrict__ bbasep,
                        int* __restrict__ bcurp, int* __restrict__ rpp,
                        const int* __restrict__ bcntn, int* __restrict__ bbasen,
                        int* __restrict__ bcurn, int* __restrict__ rpn,
                        int NB, int n, int EPv, int ENv) {
    const int* cnt = blockIdx.x ? bcntn : bcntp;
    int* bbase = blockIdx.x ? bbasen : bbasep;
    int* bcur  = blockIdx.x ? bcurn : bcurp;
    int* rp    = blockIdx.x ? rpn : rpp;
    int  E     = blockIdx.x ? ENv : EPv;
    __shared__ int s[NBMAX];
    int t = threadIdx.x;
    int v = (t < NB) ? cnt[t] : 0;
    s[t] = v;
    __syncthreads();
    for (int ofs = 1; ofs < NBMAX; ofs <<= 1) {
        int a = (t >= ofs) ? s[t - ofs] : 0;
        __syncthreads();
        s[t] += a;
        __syncthreads();
    }
    if (t < NB) {
        int excl = s[t] - v;
        bbase[t] = excl;
        bcur[t]  = excl;
    }
    if (t == NB - 1) bbase[NB] = s[t];
    if (t == 0) rp[n] = E;
}

// P2 fused: scatter edges into buckets for BOTH graphs; per-block chunk reservation.
__global__ void kb_scatter2(const int* __restrict__ row_p, const int* __restrict__ col_p,
                            const float* __restrict__ wp, int* __restrict__ bcurp,
                            int2* __restrict__ bucketP, int ep,
                            const int* __restrict__ row_n, const int* __restrict__ col_n,
                            const float* __restrict__ wn, int* __restrict__ bcurn,
                            int2* __restrict__ bucketN, int en, int gTP, int nb) {
    const int posblk = (int)blockIdx.x < gTP;
    const int* row = posblk ? row_p : row_n;
    const int* col = posblk ? col_p : col_n;
    const float* w = posblk ? wp : wn;
    int* bcur      = posblk ? bcurp : bcurn;
    int2* bucket   = posblk ? bucketP : bucketN;
    int  e         = posblk ? ep : en;
    int  tile      = posblk ? (int)blockIdx.x : (int)blockIdx.x - gTP;
    __shared__ int hist[NBMAX];
    __shared__ int cbase[NBMAX];
    int t = threadIdx.x;
    for (int b = t; b < nb; b += BLK_SC) hist[b] = 0;
    __syncthreads();
    int bs = tile * ETILE;
    int be = bs + ETILE; if (be > e) be = e;
    int i = bs + t;
    for (; i + BLK_SC < be; i += 2 * BLK_SC) {
        int r0 = row[i], r1 = row[i + BLK_SC];
        atomicAdd(&hist[r0 >> BSH], 1);
        atomicAdd(&hist[r1 >> BSH], 1);
    }
    if (i < be) atomicAdd(&hist[row[i] >> BSH], 1);
    __syncthreads();
    for (int b = t; b < nb; b += BLK_SC) {
        int c = hist[b];
        cbase[b] = c ? atomicAdd(&bcur[b], c) : 0;
        hist[b] = 0;
    }
    __syncthreads();
    i = bs + t;
    for (; i + BLK_SC < be; i += 2 * BLK_SC) {
        int i2 = i + BLK_SC;
        int r0 = row[i],  r1 = row[i2];
        int c0 = col[i],  c1 = col[i2];
        float w0 = w[i],  w1 = w[i2];
        int b0 = r0 >> BSH, b1 = r1 >> BSH;
        int rank0 = atomicAdd(&hist[b0], 1);
        int rank1 = atomicAdd(&hist[b1], 1);
        int2 p0; p0.x = c0 | ((r0 & (BROWS - 1)) << 24); p0.y = __float_as_int(w0);
        int2 p1; p1.x = c1 | ((r1 & (BROWS - 1)) << 24); p1.y = __float_as_int(w1);
        bucket[cbase[b0] + rank0] = p0;
        bucket[cbase[b1] + rank1] = p1;
    }
    if (i < be) {
        int r0 = row[i];
        int b0 = r0 >> BSH;
        int rank0 = atomicAdd(&hist[b0], 1);
        int2 p0; p0.x = col[i] | ((r0 & (BROWS - 1)) << 24); p0.y = __float_as_int(w[i]);
        bucket[cbase[b0] + rank0] = p0;
    }
}

// P3 fused: per-bucket fine CSR fill + rowptr + dinv. blockIdx < NBp -> positive graph.
__global__ void kb_fill2(const int* __restrict__ bbasep, const int2* __restrict__ bucketP,
                         int* __restrict__ rpp, float* __restrict__ dinvp,
                         int2* __restrict__ csrp,
                         const int* __restrict__ bbasen, const int2* __restrict__ bucketN,
                         int* __restrict__ rpn, float* __restrict__ dinvn,
                         int2* __restrict__ csrn, int NBp, int n) {
    const int posblk = (int)blockIdx.x < NBp;
    const int* bbase = posblk ? bbasep : bbasen;
    const int2* bucket = posblk ? bucketP : bucketN;
    int* rowptr = posblk ? rpp : rpn;
    float* dinv = posblk ? dinvp : dinvn;
    int2* csr   = posblk ? csrp : csrn;
    int bk = posblk ? (int)blockIdx.x : (int)blockIdx.x - NBp;
    int r0 = bk << BSH;
    int e0 = bbase[bk], e1 = bbase[bk + 1];
    __shared__ int   cnt[BROWS];
    __shared__ float wsm[BROWS];
    __shared__ int   sc[BROWS];
    __shared__ int   cur[BROWS];
    int t = threadIdx.x;
    cnt[t] = 0; wsm[t] = 0.0f;
    __syncthreads();
    for (int i = e0 + t; i < e1; i += BLK) {
        int2 p = bucket[i];
        int rl = (uint)p.x >> 24;
        atomicAdd(&cnt[rl], 1);
        atomicAdd(&wsm[rl], __int_as_float(p.y));
    }
    __syncthreads();
    sc[t] = cnt[t];
    __syncthreads();
    for (int ofs = 1; ofs < BROWS; ofs <<= 1) {
        int a = (t >= ofs) ? sc[t - ofs] : 0;
        __syncthreads();
        sc[t] += a;
        __syncthreads();
    }
    {
        int excl = sc[t] - cnt[t];
        int r = r0 + t;
        if (r < n) {
            rowptr[r] = e0 + excl;
            float s = wsm[t];
            dinv[r] = posblk ? 1.0f / (0.5f + s) : ((s != 0.0f) ? 1.0f / s : 0.0f);
        }
        cur[t] = e0 + excl;
    }
    __syncthreads();
    for (int i = e0 + t; i < e1; i += BLK) {
        int2 p = bucket[i];
        int rl = (uint)p.x >> 24;
        int pos = atomicAdd(&cur[rl], 1);
        int2 o; o.x = p.x & 0x00FFFFFF; o.y = p.y;
        csr[pos] = o;
    }
}

// ---------- f32 -> fp8 interleaved conversion: xq row = [64B fp8 xp | 64B fp8 xn] ----------
__global__ void k_tofp8(const float* __restrict__ xp, const float* __restrict__ xn,
                        uint* __restrict__ xq, int n) {
    int t = blockIdx.x * BLK + threadIdx.x;
    int r = t >> 4;
    if (r >= n) return;
    int j = t & 15;
    float4 a = *(const float4*)(xp + (size_t)r * D + 4 * j);
    float4 b = *(const float4*)(xn + (size_t)r * D + 4 * j);
    xq[(size_t)r * 32 + j]      = fp8x4_enc(a.x, a.y, a.z, a.w);
    xq[(size_t)r * 32 + 16 + j] = fp8x4_enc(b.x, b.y, b.z, b.w);
}

// copy xq's B half (fp8 xn) into y2q's A half (runs after buckets are dead)
__global__ void k_y2copy(const uint* __restrict__ xq, uint* __restrict__ y2q, int n) {
    int t = blockIdx.x * BLK + threadIdx.x;
    int r = t >> 4;
    if (r >= n) return;
    int j = t & 15;
    y2q[(size_t)r * 32 + j] = xq[(size_t)r * 32 + 16 + j];
}

// NT load of one CSR entry
__device__ __forceinline__ void csr_ld(const int2* __restrict__ csr, int e, int& c, float& w) {
    long long pe = __builtin_nontemporal_load((const long long*)(csr + e));
    c = (int)(unsigned int)(pe & 0xffffffffll);
    w = __int_as_float((int)(pe >> 32));
}

#define ACC8(u, v, w0) do { \
    float4 du = fp8x4_dec(u); float4 dv = fp8x4_dec(v); \
    ax += (w0) * du.x; ay += (w0) * du.y; az += (w0) * du.z; aw += (w0) * du.w; \
    bx += (w0) * dv.x; by += (w0) * dv.y; bz += (w0) * dv.z; bw += (w0) * dv.w; } while (0)

// ---------- dual gathers, fp8 interleaved sources ----------
// K1: g0 = P(xp), g1 = P(xn); t1q.A = fp8(g0), y2q.B = fp8(g1); out[:,0:64] = wp0*xp + wp1*g0
__global__ void k1_pdual(const int* __restrict__ rpp, const int2* __restrict__ csrp,
                         const float* __restrict__ dinvp,
                         const float* __restrict__ xp, const float* __restrict__ xn,
                         const uint* __restrict__ xq, const float* __restrict__ wp,
                         uint* __restrict__ t1q, uint* __restrict__ y2q,
                         float* __restrict__ out, int n) {
    int t = blockIdx.x * BLK + threadIdx.x;
    int r = t >> 4;
    if (r >= n) return;
    int j = t & 15, q = j << 2;
    const size_t rb = (size_t)r * D + q;
    float4 xpr = *(const float4*)(xp + rb);
    float4 xnr = *(const float4*)(xn + rb);
    float ax = 0.5f * xpr.x, ay = 0.5f * xpr.y, az = 0.5f * xpr.z, aw = 0.5f * xpr.w;
    float bx = 0.5f * xnr.x, by = 0.5f * xnr.y, bz = 0.5f * xnr.z, bw = 0.5f * xnr.w;
    int e = rpp[r], e1 = rpp[r + 1];
    for (; e + 1 < e1; e += 2) {
        int c0, c1i; float w0, w1;
        csr_ld(csrp, e, c0, w0);
        csr_ld(csrp, e + 1, c1i, w1);
        uint u0 = xq[(size_t)c0 * 32 + j],  v0 = xq[(size_t)c0 * 32 + 16 + j];
        uint u1 = xq[(size_t)c1i * 32 + j], v1 = xq[(size_t)c1i * 32 + 16 + j];
        ACC8(u0, v0, w0);
        ACC8(u1, v1, w1);
    }
    if (e < e1) {
        int c0; float w0;
        csr_ld(csrp, e, c0, w0);
        uint u0 = xq[(size_t)c0 * 32 + j], v0 = xq[(size_t)c0 * 32 + 16 + j];
        ACC8(u0, v0, w0);
    }
    float di = dinvp[r];
    float g0x = di * ax, g0y = di * ay, g0z = di * az, g0w = di * aw;
    float g1x = di * bx, g1y = di * by, g1z = di * bz, g1w = di * bw;
    t1q[(size_t)r * 32 + j]      = fp8x4_enc(g0x, g0y, g0z, g0w);
    y2q[(size_t)r * 32 + 16 + j] = fp8x4_enc(g1x, g1y, g1z, g1w);
    float s0 = wp[0], s1 = wp[1];
    float4 o;
    o.x = s0 * xpr.x + s1 * g0x; o.y = s0 * xpr.y + s1 * g0y;
    o.z = s0 * xpr.z + s1 * g0z; o.w = s0 * xpr.w + s1 * g0w;
    *(float4*)(out + (size_t)r * 2 * D + q) = o;
}

// K2: g0 = Nn(xn), g1 = Nn(c1); reads y2q = [xn | c1]; t1q.B = fp8(g0);
//     out[:,64:128] = wn0*g0 + wn2*g1
__global__ void k2_ndual(const int* __restrict__ rpn, const int2* __restrict__ csrn,
                         const float* __restrict__ dinvn,
                         const uint* __restrict__ y2q, const float* __restrict__ wn,
                         uint* __restrict__ t1q, float* __restrict__ out, int n) {
    int t = blockIdx.x * BLK + threadIdx.x;
    int r = t >> 4;
    if (r >= n) return;
    int j = t & 15, q = j << 2;
    float ax = 0, ay = 0, az = 0, aw = 0;
    float bx = 0, by = 0, bz = 0, bw = 0;
    int e = rpn[r], e1 = rpn[r + 1];
    for (; e + 1 < e1; e += 2) {
        int c0, c1i; float w0, w1;
        csr_ld(csrn, e, c0, w0);
        csr_ld(csrn, e + 1, c1i, w1);
        uint u0 = y2q[(size_t)c0 * 32 + j],  v0 = y2q[(size_t)c0 * 32 + 16 + j];
        uint u1 = y2q[(size_t)c1i * 32 + j], v1 = y2q[(size_t)c1i * 32 + 16 + j];
        ACC8(u0, v0, w0);
        ACC8(u1, v1, w1);
    }
    if (e < e1) {
        int c0; float w0;
        csr_ld(csrn, e, c0, w0);
        uint u0 = y2q[(size_t)c0 * 32 + j], v0 = y2q[(size_t)c0 * 32 + 16 + j];
        ACC8(u0, v0, w0);
    }
    float di = dinvn[r];
    float g0x = di * ax, g0y = di * ay, g0z = di * az, g0w = di * aw;
    float g1x = di * bx, g1y = di * by, g1z = di * bz, g1w = di * bw;
    t1q[(size_t)r * 32 + 16 + j] = fp8x4_enc(g0x, g0y, g0z, g0w);
    float s0 = wn[0], s2 = wn[2];
    float4 o;
    o.x = s0 * g0x + s2 * g1x; o.y = s0 * g0y + s2 * g1y;
    o.z = s0 * g0z + s2 * g1z; o.w = s0 * g0w + s2 * g1w;
    *(float4*)(out + (size_t)r * 2 * D + D + q) = o;
}

// K3: out[:,0:64] += wp2*P(a1) ; out[:,64:128] += wn1*P(b1)  (a1,b1 = t1q A/B)
__global__ void k3_pdual(const int* __restrict__ rpp, const int2* __restrict__ csrp,
                         const float* __restrict__ dinvp,
                         const uint* __restrict__ t1q,
                         const float* __restrict__ wp, const float* __restrict__ wn,
                         float* __restrict__ out, int n) {
    int t = blockIdx.x * BLK + threadIdx.x;
    int r = t >> 4;
    if (r >= n) return;
    int j = t & 15, q = j << 2;
    float4 ar = fp8x4_dec(t1q[(size_t)r * 32 + j]);
    float4 br = fp8x4_dec(t1q[(size_t)r * 32 + 16 + j]);
    float ax = 0.5f * ar.x, ay = 0.5f * ar.y, az = 0.5f * ar.z, aw = 0.5f * ar.w;
    float bx = 0.5f * br.x, by = 0.5f * br.y, bz = 0.5f * br.z, bw = 0.5f * br.w;
    int e = rpp[r], e1 = rpp[r + 1];
    for (; e + 1 < e1; e += 2) {
        int c0, c1i; float w0, w1;
        csr_ld(csrp, e, c0, w0);
        csr_ld(csrp, e + 1, c1i, w1);
        uint u0 = t1q[(size_t)c0 * 32 + j],  v0 = t1q[(size_t)c0 * 32 + 16 + j];
        uint u1 = t1q[(size_t)c1i * 32 + j], v1 = t1q[(size_t)c1i * 32 + 16 + j];
        ACC8(u0, v0, w0);
        ACC8(u1, v1, w1);
    }
    if (e < e1) {
        int c0; float w0;
        csr_ld(csrp, e, c0, w0);
        uint u0 = t1q[(size_t)c0 * 32 + j], v0 = t1q[(size_t)c0 * 32 + 16 + j];
        ACC8(u0, v0, w0);
    }
    float di = dinvp[r];
    float sp = wp[2] * di, sn = wn[1] * di;
    float* po0 = out + (size_t)r * 2 * D + q;
    float* po1 = po0 + D;
    float4 o0 = *(const float4*)po0;
    float4 o1 = *(const float4*)po1;
    o0.x += sp * ax; o0.y += sp * ay; o0.z += sp * az; o0.w += sp * aw;
    o1.x += sn * bx; o1.y += sn * by; o1.z += sn * bz; o1.w += sn * bw;
    *(float4*)po0 = o0;
    *(float4*)po1 = o1;
}

// ---------- Tier C fallback: atomic path ----------
__global__ void kc_init(float* dp, float* dn, int n) {
    int i = blockIdx.x * BLK + threadIdx.x;
    if (i < n) { dp[i] = 0.5f; dn[i] = 0.0f; }
}
__global__ void kc_accum(const int* __restrict__ row, const float* __restrict__ w,
                         float* __restrict__ deg, int e) {
    int i = blockIdx.x * BLK + threadIdx.x;
    if (i < e) atomicAdd(&deg[row[i]], w[i]);
}
__global__ void kc_inv(float* dp, float* dn, int n) {
    int i = blockIdx.x * BLK + threadIdx.x;
    if (i < n) {
        float a = dp[i]; dp[i] = (a != 0.f) ? 1.f / a : 0.f;
        float b = dn[i]; dn[i] = (b != 0.f) ? 1.f / b : 0.f;
    }
}
__global__ void kc_base(float* __restrict__ out, const float* __restrict__ xp,
                        const float* __restrict__ wp, int n) {
    int tid = blockIdx.x * BLK + threadIdx.x;
    if (tid < n * 2 * D) {
        int i = tid >> 7, l = tid & 127;
        out[tid] = (l < D) ? wp[0] * xp[i * D + l] : 0.0f;
    }
}
__global__ void kc_selfinit(const float* dinv, const float* x, float* y, int nd) {
    int t = blockIdx.x * BLK + threadIdx.x;
    if (t < nd) { int i = t >> 6; y[t] = 0.5f * dinv[i] * x[t]; }
}
__global__ void kc_zero(float* y, int nd) {
    int t = blockIdx.x * BLK + threadIdx.x;
    if (t < nd) y[t] = 0.0f;
}
__global__ void kc_scatter(const int* row, const int* col, const float* w,
                           const float* dinv, const float* x, float* y, int e) {
    int t = blockIdx.x * BLK + threadIdx.x;
    int edge = t >> 6;
    if (edge < e) {
        int l = t & 63;
        int r = row[edge], c = col[edge];
        atomicAdd(&y[r * D + l], dinv[r] * w[edge] * x[c * D + l]);
    }
}
__global__ void kc_axpy(float* out, const float* src, const float* wv, int wi, int off, int nd) {
    int t = blockIdx.x * BLK + threadIdx.x;
    if (t < nd) {
        int i = t >> 6, l = t & 63;
        out[i * 2 * D + off + l] += wv[wi] * src[t];
    }
}

extern "C" void kernel_launch(void* const* d_in, const int* in_sizes, int n_in,
                              void* d_out, int out_size, void* d_ws, size_t ws_size,
                              hipStream_t stream) {
    const int*   eip = (const int*)  d_in[0];
    const float* ewp = (const float*)d_in[1];
    const int*   ein = (const int*)  d_in[2];
    const float* ewn = (const float*)d_in[3];
    const float* xp  = (const float*)d_in[4];
    const float* xn  = (const float*)d_in[5];
    const float* wp  = (const float*)d_in[6];
    const float* wn  = (const float*)d_in[7];

    const int EP = in_sizes[0] / 2;
    const int EN = in_sizes[2] / 2;
    const int n  = in_sizes[4] / D;
    const int nd = n * D;
    const int NB = cdiv(n, BROWS);

    const int* row_p = eip;
    const int* col_p = eip + EP;
    const int* row_n = ein;
    const int* col_n = ein + EN;

    float* out = (float*)d_out;

    const int gN   = cdiv(n, BLK);
    const int gEP1 = cdiv(EP, BLK);
    const int gEN1 = cdiv(EN, BLK);
    const int g16  = cdiv((long)n * 16, BLK);
    const int gTP  = cdiv(EP, ETILE);
    const int gTN  = cdiv(EN, ETILE);

    // ---- ws layout (dwords): csrp | csrn | X (buckets -> t1q,y2q) | xq | header ----
    size_t csrE = (size_t)2 * EP + (size_t)2 * EN;
    size_t Xsz  = (size_t)2 * EP + (size_t)2 * EN;          // buckets
    size_t tmpE = (size_t)nd / 2 + (size_t)nd / 2;          // t1q + y2q
    if (tmpE > Xsz) Xsz = tmpE;
    Xsz = (Xsz + 3) & ~(size_t)3;
    size_t xqE  = (size_t)nd / 2;                            // fp8 interleaved inputs
    size_t hdr  = 4 * (size_t)n + 2 + 6 * (size_t)NBMAX + 2 + 16;
    size_t need = csrE + Xsz + xqE + hdr;

    if (ws_size >= need * 4 && NB <= NBMAX && n < (1 << 24)) {
        int*  base = (int*)d_ws;
        int2* csrp = (int2*)base;
        int2* csrn = (int2*)(base + (size_t)2 * EP);
        int*  X    = base + csrE;
        int2* bucketP = (int2*)X;
        int2* bucketN = bucketP + EP;
        uint* t1q = (uint*)X;                    // n*32 dwords, rows [fp8 a1 | fp8 b1]
        uint* y2q = t1q + (size_t)nd / 2;        // n*32 dwords, rows [fp8 xn | fp8 c1]
        uint* xq  = (uint*)(X + Xsz);            // n*32 dwords, rows [fp8 xp | fp8 xn]
        int* ip = X + Xsz + xqE;
        float* dinvp = (float*)ip;  ip += n;
        float* dinvn = (float*)ip;  ip += n;
        int* rpp = ip;              ip += n + 1;
        int* rpn = ip;              ip += n + 1;
        int* bcntp = ip;            ip += NBMAX;
        int* bcntn = ip;            ip += NBMAX;
        int* bbasep = ip;           ip += NBMAX + 1;
        int* bbasen = ip;           ip += NBMAX + 1;
        int* bcurp = ip;            ip += NBMAX;
        int* bcurn = ip;

        // ---- bucketed build (fused P+N, doubled grid via ETILE=8192) + fp8 conversion ----
        k_zb<<<cdiv(NBMAX, BLK), BLK, 0, stream>>>(bcntp, bcntn);
        k_tofp8<<<g16, BLK, 0, stream>>>(xp, xn, xq, n);
        kb_count2<<<gTP + gTN, BLK_SC, 0, stream>>>(row_p, bcntp, EP,
                                                    row_n, bcntn, EN, gTP, NB);
        kb_scan<<<2, NBMAX, 0, stream>>>(bcntp, bbasep, bcurp, rpp,
                                         bcntn, bbasen, bcurn, rpn, NB, n, EP, EN);
        kb_scatter2<<<gTP + gTN, BLK_SC, 0, stream>>>(row_p, col_p, ewp, bcurp, bucketP, EP,
                                                      row_n, col_n, ewn, bcurn, bucketN, EN,
                                                      gTP, NB);
        kb_fill2<<<2 * NB, BLK, 0, stream>>>(bbasep, bucketP, rpp, dinvp, csrp,
                                             bbasen, bucketN, rpn, dinvn, csrn, NB, n);

        // ---- interleave setup + 3 dual gathers (t1q/y2q overwrite dead buckets) ----
        k_y2copy<<<g16, BLK, 0, stream>>>(xq, y2q, n);
        k1_pdual<<<g16, BLK, 0, stream>>>(rpp, csrp, dinvp, xp, xn, xq, wp, t1q, y2q, out, n);
        k2_ndual<<<g16, BLK, 0, stream>>>(rpn, csrn, dinvn, y2q, wn, t1q, out, n);
        k3_pdual<<<g16, BLK, 0, stream>>>(rpp, csrp, dinvp, t1q, wp, wn, out, n);
        return;
    }

    // ---------------- Tier C: atomic-scatter fallback ----------------
    float* ws    = (float*)d_ws;
    float* dinvp = ws;
    float* dinvn = ws + n;
    float* t0    = ws + 2 * n;
    float* t1    = t0 + (size_t)nd;

    const int gND  = cdiv(nd, BLK);
    const int gOUT = cdiv((long)n * 2 * D, BLK);
    const int gEPd = cdiv((long)EP * D, BLK);
    const int gENd = cdiv((long)EN * D, BLK);

    kc_init<<<gN, BLK, 0, stream>>>(dinvp, dinvn, n);
    kc_accum<<<gEP1, BLK, 0, stream>>>(row_p, ewp, dinvp, EP);
    kc_accum<<<gEN1, BLK, 0, stream>>>(row_n, ewn, dinvn, EN);
    kc_inv<<<gN, BLK, 0, stream>>>(dinvp, dinvn, n);

    kc_base<<<gOUT, BLK, 0, stream>>>(out, xp, wp, n);

    kc_selfinit<<<gND, BLK, 0, stream>>>(dinvp, xp, t0, nd);
    kc_scatter<<<gEPd, BLK, 0, stream>>>(row_p, col_p, ewp, dinvp, xp, t0, EP);
    kc_axpy<<<gND, BLK, 0, stream>>>(out, t0, wp, 1, 0, nd);

    kc_selfinit<<<gND, BLK, 0, stream>>>(dinvp, t0, t1, nd);
    kc_scatter<<<gEPd, BLK, 0, stream>>>(row_p, col_p, ewp, dinvp, t0, t1, EP);
    kc_axpy<<<gND, BLK, 0, stream>>>(out, t1, wp, 2, 0, nd);

    kc_zero<<<gND, BLK, 0, stream>>>(t1, nd);
    kc_scatter<<<gENd, BLK, 0, stream>>>(row_n, col_n, ewn, dinvn, xn, t1, EN);
    kc_axpy<<<gND, BLK, 0, stream>>>(out, t1, wn, 0, D, nd);

    kc_selfinit<<<gND, BLK, 0, stream>>>(dinvp, t1, t0, nd);
    kc_scatter<<<gEPd, BLK, 0, stream>>>(row_p, col_p, ewp, dinvp, t1, t0, EP);
    kc_axpy<<<gND, BLK, 0, stream>>>(out, t0, wn, 1, D, nd);

    kc_selfinit<<<gND, BLK, 0, stream>>>(dinvp, xn, t0, nd);
    kc_scatter<<<gEPd, BLK, 0, stream>>>(row_p, col_p, ewp, dinvp, xn, t0, EP);

    kc_zero<<<gND, BLK, 0, stream>>>(t1, nd);
    kc_scatter<<<gENd, BLK, 0, stream>>>(row_n, col_n, ewn, dinvn, t0, t1, EN);
    kc_axpy<<<gND, BLK, 0, stream>>>(out, t1, wn, 2, D, nd);
}

// Round 12
// 422.587 us; speedup vs baseline: 1.0054x; 1.0054x over previous
//
#include <hip/hip_runtime.h>

#define D 64
#define BLK 256
#define BLK_SC 1024         // big blocks for the latency-bound bucket passes
#define BSH 8               // bucket = 256 rows
#define BROWS 256
#define NBMAX 1024
#define ETILE 8192          // legacy scatter tile
#define NBSZ 512            // staged-scatter bucket capacity (n <= 131072)
#define ETILE_S 6144        // staged scatter tile (56 KB LDS)

typedef unsigned int uint;
typedef float floatx2 __attribute__((ext_vector_type(2)));

static inline int cdiv(long a, long b) { return (int)((a + b - 1) / b); }

// ---------------- fp8 e4m3 helpers (HW converts on gfx950, OCP format) ----------------
#if defined(__has_builtin) && __has_builtin(__builtin_amdgcn_cvt_pk_f32_fp8) && __has_builtin(__builtin_amdgcn_cvt_pk_fp8_f32)
__device__ __forceinline__ float4 fp8x4_dec(uint u) {
    floatx2 lo = __builtin_amdgcn_cvt_pk_f32_fp8((int)u, false);
    floatx2 hi = __builtin_amdgcn_cvt_pk_f32_fp8((int)u, true);
    float4 r; r.x = lo[0]; r.y = lo[1]; r.z = hi[0]; r.w = hi[1];
    return r;
}
__device__ __forceinline__ uint fp8x4_enc(float a, float b, float c, float d) {
    int v = __builtin_amdgcn_cvt_pk_fp8_f32(a, b, 0, false);
    v = __builtin_amdgcn_cvt_pk_fp8_f32(c, d, v, true);
    return (uint)v;
}
#else
__device__ __forceinline__ float fp8_dec1(uint b) {
    uint s = (b >> 7) & 1u, e = (b >> 3) & 15u, m = b & 7u;
    float v = e ? __uint_as_float(((e + 120u) << 23) | (m << 20))
                : (float)m * 0.001953125f;
    return s ? -v : v;
}
__device__ __forceinline__ uint fp8_enc1(float f) {
    uint u = __float_as_uint(f);
    uint s = (u >> 31) << 7;
    float a = fabsf(f);
    if (a >= 448.0f) return s | 0x7Eu;
    if (a < 0.001953125f) {
        uint m = (uint)(a * 512.0f + 0.5f);
        return s | (m > 7u ? 7u : m);
    }
    int e = (int)((u >> 23) & 0xFF) - 127;
    uint mant = (u >> 20) & 7u;
    uint rest = u & 0xFFFFFu;
    if (rest > 0x80000u || (rest == 0x80000u && (mant & 1u))) {
        mant++; if (mant == 8u) { mant = 0u; e++; }
    }
    if (e > 8) return s | 0x7Eu;
    if (e < -6) { uint m = (uint)(a * 512.0f + 0.5f); return s | (m > 7u ? 7u : m); }
    return s | ((uint)(e + 7) << 3) | mant;
}
__device__ __forceinline__ float4 fp8x4_dec(uint u) {
    float4 r;
    r.x = fp8_dec1(u & 0xFF); r.y = fp8_dec1((u >> 8) & 0xFF);
    r.z = fp8_dec1((u >> 16) & 0xFF); r.w = fp8_dec1(u >> 24);
    return r;
}
__device__ __forceinline__ uint fp8x4_enc(float a, float b, float c, float d) {
    return fp8_enc1(a) | (fp8_enc1(b) << 8) | (fp8_enc1(c) << 16) | (fp8_enc1(d) << 24);
}
#endif

// ---------------- bucketed CSR build ----------------
__global__ void k_zb(int* __restrict__ a, int* __restrict__ b) {
    int i = blockIdx.x * BLK + threadIdx.x;
    if (i < NBMAX) { a[i] = 0; b[i] = 0; }
}

// P1 fused: bucket histogram for BOTH graphs; blockIdx < gTP -> positive.
__global__ void kb_count2(const int* __restrict__ row_p, int* __restrict__ bcntp, int ep,
                          const int* __restrict__ row_n, int* __restrict__ bcntn, int en,
                          int gTP, int nb, int etile) {
    const int posblk = (int)blockIdx.x < gTP;
    const int* row = posblk ? row_p : row_n;
    int* bcnt      = posblk ? bcntp : bcntn;
    int  e         = posblk ? ep : en;
    int  tile      = posblk ? (int)blockIdx.x : (int)blockIdx.x - gTP;
    __shared__ int hist[NBMAX];
    int t = threadIdx.x;
    for (int b = t; b < nb; b += BLK_SC) hist[b] = 0;
    __syncthreads();
    int bs = tile * etile;
    int be = bs + etile; if (be > e) be = e;
    int i = bs + t;
    for (; i + BLK_SC < be; i += 2 * BLK_SC) {
        int r0 = row[i], r1 = row[i + BLK_SC];
        atomicAdd(&hist[r0 >> BSH], 1);
        atomicAdd(&hist[r1 >> BSH], 1);
    }
    if (i < be) atomicAdd(&hist[row[i] >> BSH], 1);
    __syncthreads();
    for (int b = t; b < nb; b += BLK_SC) {
        int c = hist[b];
        if (c) atomicAdd(&bcnt[b], c);
    }
}

__global__ void kb_scan(const int* __restrict__ bcntp, int* __restrict__ bbasep,
                        int* __restrict__ bcurp, int* __restrict__ rpp,
                        const int* __restrict__ bcntn, int* __restrict__ bbasen,
                        int* __restrict__ bcurn, int* __restrict__ rpn,
                        int NB, int n, int EPv, int ENv) {
    const int* cnt = blockIdx.x ? bcntn : bcntp;
    int* bbase = blockIdx.x ? bbasen : bbasep;
    int* bcur  = blockIdx.x ? bcurn : bcurp;
    int* rp    = blockIdx.x ? rpn : rpp;
    int  E     = blockIdx.x ? ENv : EPv;
    __shared__ int s[NBMAX];
    int t = threadIdx.x;
    int v = (t < NB) ? cnt[t] : 0;
    s[t] = v;
    __syncthreads();
    for (int ofs = 1; ofs < NBMAX; ofs <<= 1) {
        int a = (t >= ofs) ? s[t - ofs] : 0;
        __syncthreads();
        s[t] += a;
        __syncthreads();
    }
    if (t < NB) {
        int excl = s[t] - v;
        bbase[t] = excl;
        bcur[t]  = excl;
    }
    if (t == NB - 1) bbase[NB] = s[t];
    if (t == 0) rp[n] = E;
}

// P2 staged: LDS counting-sort of the tile by bucket, then wave-per-bucket coalesced drain.
__global__ void kb_scatter2s(const int* __restrict__ row_p, const int* __restrict__ col_p,
                             const float* __restrict__ wp, int* __restrict__ bcurp,
                             int2* __restrict__ bucketP, int ep,
                             const int* __restrict__ row_n, const int* __restrict__ col_n,
                             const float* __restrict__ wn, int* __restrict__ bcurn,
                             int2* __restrict__ bucketN, int en, int gTP, int nb) {
    const int posblk = (int)blockIdx.x < gTP;
    const int* row = posblk ? row_p : row_n;
    const int* col = posblk ? col_p : col_n;
    const float* w = posblk ? wp : wn;
    int* bcur      = posblk ? bcurp : bcurn;
    int2* bucket   = posblk ? bucketP : bucketN;
    int  e         = posblk ? ep : en;
    int  tile      = posblk ? (int)blockIdx.x : (int)blockIdx.x - gTP;
    __shared__ int  hist[NBSZ];
    __shared__ int  lbase[NBSZ];
    __shared__ int  cbase[NBSZ];
    __shared__ int  rankc[NBSZ];
    __shared__ int2 stage[ETILE_S];
    int t = threadIdx.x;
    for (int b = t; b < NBSZ; b += BLK_SC) { hist[b] = 0; rankc[b] = 0; }
    __syncthreads();
    int bs = tile * ETILE_S;
    int be = bs + ETILE_S; if (be > e) be = e;
    // phase B: per-block bucket histogram
    for (int i = bs + t; i < be; i += BLK_SC) atomicAdd(&hist[row[i] >> BSH], 1);
    __syncthreads();
    // phase C: exclusive scan hist -> lbase (512 entries, threads t<NBSZ), chunk reservation
    {
        int v = (t < NBSZ) ? hist[t] : 0;
        if (t < NBSZ) lbase[t] = v;
        __syncthreads();
        for (int ofs = 1; ofs < NBSZ; ofs <<= 1) {
            int a = (t < NBSZ && t >= ofs) ? lbase[t - ofs] : 0;
            __syncthreads();
            if (t < NBSZ) lbase[t] += a;
            __syncthreads();
        }
        if (t < NBSZ) {
            lbase[t] -= v;                                        // inclusive -> exclusive
            cbase[t] = v ? atomicAdd(&bcur[t], v) : 0;            // global chunk base
        }
    }
    __syncthreads();
    // phase D: counting-sort edges into LDS stage (ordered by bucket)
    for (int i = bs + t; i < be; i += BLK_SC) {
        int r = row[i];
        int b = r >> BSH;
        int rk = atomicAdd(&rankc[b], 1);
        int2 p;
        p.x = col[i] | ((r & (BROWS - 1)) << 24);
        p.y = __float_as_int(w[i]);
        stage[lbase[b] + rk] = p;
    }
    __syncthreads();
    // phase E: wave-per-bucket drain; consecutive lanes -> consecutive global addrs
    int wid = t >> 6, lane = t & 63;
    for (int b = wid; b < nb; b += (BLK_SC >> 6)) {
        int cnt = hist[b];
        int lb = lbase[b], cb = cbase[b];
        for (int k = lane; k < cnt; k += 64) bucket[cb + k] = stage[lb + k];
    }
}

// P2 legacy (NB > NBSZ): direct scattered chunk writes
__global__ void kb_scatter2(const int* __restrict__ row_p, const int* __restrict__ col_p,
                            const float* __restrict__ wp, int* __restrict__ bcurp,
                            int2* __restrict__ bucketP, int ep,
                            const int* __restrict__ row_n, const int* __restrict__ col_n,
                            const float* __restrict__ wn, int* __restrict__ bcurn,
                            int2* __restrict__ bucketN, int en, int gTP, int nb) {
    const int posblk = (int)blockIdx.x < gTP;
    const int* row = posblk ? row_p : row_n;
    const int* col = posblk ? col_p : col_n;
    const float* w = posblk ? wp : wn;
    int* bcur      = posblk ? bcurp : bcurn;
    int2* bucket   = posblk ? bucketP : bucketN;
    int  e         = posblk ? ep : en;
    int  tile      = posblk ? (int)blockIdx.x : (int)blockIdx.x - gTP;
    __shared__ int hist[NBMAX];
    __shared__ int cbase[NBMAX];
    int t = threadIdx.x;
    for (int b = t; b < nb; b += BLK_SC) hist[b] = 0;
    __syncthreads();
    int bs = tile * ETILE;
    int be = bs + ETILE; if (be > e) be = e;
    for (int i = bs + t; i < be; i += BLK_SC) atomicAdd(&hist[row[i] >> BSH], 1);
    __syncthreads();
    for (int b = t; b < nb; b += BLK_SC) {
        int c = hist[b];
        cbase[b] = c ? atomicAdd(&bcur[b], c) : 0;
        hist[b] = 0;
    }
    __syncthreads();
    for (int i = bs + t; i < be; i += BLK_SC) {
        int r = row[i];
        int b = r >> BSH;
        int rank = atomicAdd(&hist[b], 1);
        int2 p;
        p.x = col[i] | ((r & (BROWS - 1)) << 24);
        p.y = __float_as_int(w[i]);
        bucket[cbase[b] + rank] = p;
    }
}

// P3 fused: per-bucket fine CSR fill + rowptr + dinv. blockIdx < NBp -> positive graph.
__global__ void kb_fill2(const int* __restrict__ bbasep, const int2* __restrict__ bucketP,
                         int* __restrict__ rpp, float* __restrict__ dinvp,
                         int2* __restrict__ csrp,
                         const int* __restrict__ bbasen, const int2* __restrict__ bucketN,
                         int* __restrict__ rpn, float* __restrict__ dinvn,
                         int2* __restrict__ csrn, int NBp, int n) {
    const int posblk = (int)blockIdx.x < NBp;
    const int* bbase = posblk ? bbasep : bbasen;
    const int2* bucket = posblk ? bucketP : bucketN;
    int* rowptr = posblk ? rpp : rpn;
    float* dinv = posblk ? dinvp : dinvn;
    int2* csr   = posblk ? csrp : csrn;
    int bk = posblk ? (int)blockIdx.x : (int)blockIdx.x - NBp;
    int r0 = bk << BSH;
    int e0 = bbase[bk], e1 = bbase[bk + 1];
    __shared__ int   cnt[BROWS];
    __shared__ float wsm[BROWS];
    __shared__ int   sc[BROWS];
    __shared__ int   cur[BROWS];
    int t = threadIdx.x;
    cnt[t] = 0; wsm[t] = 0.0f;
    __syncthreads();
    for (int i = e0 + t; i < e1; i += BLK) {
        int2 p = bucket[i];
        int rl = (uint)p.x >> 24;
        atomicAdd(&cnt[rl], 1);
        atomicAdd(&wsm[rl], __int_as_float(p.y));
    }
    __syncthreads();
    sc[t] = cnt[t];
    __syncthreads();
    for (int ofs = 1; ofs < BROWS; ofs <<= 1) {
        int a = (t >= ofs) ? sc[t - ofs] : 0;
        __syncthreads();
        sc[t] += a;
        __syncthreads();
    }
    {
        int excl = sc[t] - cnt[t];
        int r = r0 + t;
        if (r < n) {
            rowptr[r] = e0 + excl;
            float s = wsm[t];
            dinv[r] = posblk ? 1.0f / (0.5f + s) : ((s != 0.0f) ? 1.0f / s : 0.0f);
        }
        cur[t] = e0 + excl;
    }
    __syncthreads();
    for (int i = e0 + t; i < e1; i += BLK) {
        int2 p = bucket[i];
        int rl = (uint)p.x >> 24;
        int pos = atomicAdd(&cur[rl], 1);
        int2 o; o.x = p.x & 0x00FFFFFF; o.y = p.y;
        csr[pos] = o;
    }
}

// ---------- f32 -> fp8 interleaved conversion: xq row = [64B fp8 xp | 64B fp8 xn] ----------
__global__ void k_tofp8(const float* __restrict__ xp, const float* __restrict__ xn,
                        uint* __restrict__ xq, int n) {
    int t = blockIdx.x * BLK + threadIdx.x;
    int r = t >> 4;
    if (r >= n) return;
    int j = t & 15;
    float4 a = *(const float4*)(xp + (size_t)r * D + 4 * j);
    float4 b = *(const float4*)(xn + (size_t)r * D + 4 * j);
    xq[(size_t)r * 32 + j]      = fp8x4_enc(a.x, a.y, a.z, a.w);
    xq[(size_t)r * 32 + 16 + j] = fp8x4_enc(b.x, b.y, b.z, b.w);
}

// copy xq's B half (fp8 xn) into y2q's A half (runs after buckets are dead)
__global__ void k_y2copy(const uint* __restrict__ xq, uint* __restrict__ y2q, int n) {
    int t = blockIdx.x * BLK + threadIdx.x;
    int r = t >> 4;
    if (r >= n) return;
    int j = t & 15;
    y2q[(size_t)r * 32 + j] = xq[(size_t)r * 32 + 16 + j];
}

// NT load of one CSR entry
__device__ __forceinline__ void csr_ld(const int2* __restrict__ csr, int e, int& c, float& w) {
    long long pe = __builtin_nontemporal_load((const long long*)(csr + e));
    c = (int)(unsigned int)(pe & 0xffffffffll);
    w = __int_as_float((int)(pe >> 32));
}

#define ACC8(u, v, w0) do { \
    float4 du = fp8x4_dec(u); float4 dv = fp8x4_dec(v); \
    ax += (w0) * du.x; ay += (w0) * du.y; az += (w0) * du.z; aw += (w0) * du.w; \
    bx += (w0) * dv.x; by += (w0) * dv.y; bz += (w0) * dv.z; bw += (w0) * dv.w; } while (0)

// ---------- dual gathers, fp8 interleaved sources ----------
__global__ void k1_pdual(const int* __restrict__ rpp, const int2* __restrict__ csrp,
                         const float* __restrict__ dinvp,
                         const float* __restrict__ xp, const float* __restrict__ xn,
                         const uint* __restrict__ xq, const float* __restrict__ wp,
                         uint* __restrict__ t1q, uint* __restrict__ y2q,
                         float* __restrict__ out, int n) {
    int t = blockIdx.x * BLK + threadIdx.x;
    int r = t >> 4;
    if (r >= n) return;
    int j = t & 15, q = j << 2;
    const size_t rb = (size_t)r * D + q;
    float4 xpr = *(const float4*)(xp + rb);
    float4 xnr = *(const float4*)(xn + rb);
    float ax = 0.5f * xpr.x, ay = 0.5f * xpr.y, az = 0.5f * xpr.z, aw = 0.5f * xpr.w;
    float bx = 0.5f * xnr.x, by = 0.5f * xnr.y, bz = 0.5f * xnr.z, bw = 0.5f * xnr.w;
    int e = rpp[r], e1 = rpp[r + 1];
    for (; e + 1 < e1; e += 2) {
        int c0, c1i; float w0, w1;
        csr_ld(csrp, e, c0, w0);
        csr_ld(csrp, e + 1, c1i, w1);
        uint u0 = xq[(size_t)c0 * 32 + j],  v0 = xq[(size_t)c0 * 32 + 16 + j];
        uint u1 = xq[(size_t)c1i * 32 + j], v1 = xq[(size_t)c1i * 32 + 16 + j];
        ACC8(u0, v0, w0);
        ACC8(u1, v1, w1);
    }
    if (e < e1) {
        int c0; float w0;
        csr_ld(csrp, e, c0, w0);
        uint u0 = xq[(size_t)c0 * 32 + j], v0 = xq[(size_t)c0 * 32 + 16 + j];
        ACC8(u0, v0, w0);
    }
    float di = dinvp[r];
    float g0x = di * ax, g0y = di * ay, g0z = di * az, g0w = di * aw;
    float g1x = di * bx, g1y = di * by, g1z = di * bz, g1w = di * bw;
    t1q[(size_t)r * 32 + j]      = fp8x4_enc(g0x, g0y, g0z, g0w);
    y2q[(size_t)r * 32 + 16 + j] = fp8x4_enc(g1x, g1y, g1z, g1w);
    float s0 = wp[0], s1 = wp[1];
    float4 o;
    o.x = s0 * xpr.x + s1 * g0x; o.y = s0 * xpr.y + s1 * g0y;
    o.z = s0 * xpr.z + s1 * g0z; o.w = s0 * xpr.w + s1 * g0w;
    *(float4*)(out + (size_t)r * 2 * D + q) = o;
}

__global__ void k2_ndual(const int* __restrict__ rpn, const int2* __restrict__ csrn,
                         const float* __restrict__ dinvn,
                         const uint* __restrict__ y2q, const float* __restrict__ wn,
                         uint* __restrict__ t1q, float* __restrict__ out, int n) {
    int t = blockIdx.x * BLK + threadIdx.x;
    int r = t >> 4;
    if (r >= n) return;
    int j = t & 15, q = j << 2;
    float ax = 0, ay = 0, az = 0, aw = 0;
    float bx = 0, by = 0, bz = 0, bw = 0;
    int e = rpn[r], e1 = rpn[r + 1];
    for (; e + 1 < e1; e += 2) {
        int c0, c1i; float w0, w1;
        csr_ld(csrn, e, c0, w0);
        csr_ld(csrn, e + 1, c1i, w1);
        uint u0 = y2q[(size_t)c0 * 32 + j],  v0 = y2q[(size_t)c0 * 32 + 16 + j];
        uint u1 = y2q[(size_t)c1i * 32 + j], v1 = y2q[(size_t)c1i * 32 + 16 + j];
        ACC8(u0, v0, w0);
        ACC8(u1, v1, w1);
    }
    if (e < e1) {
        int c0; float w0;
        csr_ld(csrn, e, c0, w0);
        uint u0 = y2q[(size_t)c0 * 32 + j], v0 = y2q[(size_t)c0 * 32 + 16 + j];
        ACC8(u0, v0, w0);
    }
    float di = dinvn[r];
    float g0x = di * ax, g0y = di * ay, g0z = di * az, g0w = di * aw;
    float g1x = di * bx, g1y = di * by, g1z = di * bz, g1w = di * bw;
    t1q[(size_t)r * 32 + 16 + j] = fp8x4_enc(g0x, g0y, g0z, g0w);
    float s0 = wn[0], s2 = wn[2];
    float4 o;
    o.x = s0 * g0x + s2 * g1x; o.y = s0 * g0y + s2 * g1y;
    o.z = s0 * g0z + s2 * g1z; o.w = s0 * g0w + s2 * g1w;
    *(float4*)(out + (size_t)r * 2 * D + D + q) = o;
}

__global__ void k3_pdual(const int* __restrict__ rpp, const int2* __restrict__ csrp,
                         const float* __restrict__ dinvp,
                         const uint* __restrict__ t1q,
                         const float* __restrict__ wp, const float* __restrict__ wn,
                         float* __restrict__ out, int n) {
    int t = blockIdx.x * BLK + threadIdx.x;
    int r = t >> 4;
    if (r >= n) return;
    int j = t & 15, q = j << 2;
    float4 ar = fp8x4_dec(t1q[(size_t)r * 32 + j]);
    float4 br = fp8x4_dec(t1q[(size_t)r * 32 + 16 + j]);
    float ax = 0.5f * ar.x, ay = 0.5f * ar.y, az = 0.5f * ar.z, aw = 0.5f * ar.w;
    float bx = 0.5f * br.x, by = 0.5f * br.y, bz = 0.5f * br.z, bw = 0.5f * br.w;
    int e = rpp[r], e1 = rpp[r + 1];
    for (; e + 1 < e1; e += 2) {
        int c0, c1i; float w0, w1;
        csr_ld(csrp, e, c0, w0);
        csr_ld(csrp, e + 1, c1i, w1);
        uint u0 = t1q[(size_t)c0 * 32 + j],  v0 = t1q[(size_t)c0 * 32 + 16 + j];
        uint u1 = t1q[(size_t)c1i * 32 + j], v1 = t1q[(size_t)c1i * 32 + 16 + j];
        ACC8(u0, v0, w0);
        ACC8(u1, v1, w1);
    }
    if (e < e1) {
        int c0; float w0;
        csr_ld(csrp, e, c0, w0);
        uint u0 = t1q[(size_t)c0 * 32 + j], v0 = t1q[(size_t)c0 * 32 + 16 + j];
        ACC8(u0, v0, w0);
    }
    float di = dinvp[r];
    float sp = wp[2] * di, sn = wn[1] * di;
    float* po0 = out + (size_t)r * 2 * D + q;
    float* po1 = po0 + D;
    float4 o0 = *(const float4*)po0;
    float4 o1 = *(const float4*)po1;
    o0.x += sp * ax; o0.y += sp * ay; o0.z += sp * az; o0.w += sp * aw;
    o1.x += sn * bx; o1.y += sn * by; o1.z += sn * bz; o1.w += sn * bw;
    *(float4*)po0 = o0;
    *(float4*)po1 = o1;
}

// ---------- Tier C fallback: atomic path ----------
__global__ void kc_init(float* dp, float* dn, int n) {
    int i = blockIdx.x * BLK + threadIdx.x;
    if (i < n) { dp[i] = 0.5f; dn[i] = 0.0f; }
}
__global__ void kc_accum(const int* __restrict__ row, const float* __restrict__ w,
                         float* __restrict__ deg, int e) {
    int i = blockIdx.x * BLK + threadIdx.x;
    if (i < e) atomicAdd(&deg[row[i]], w[i]);
}
__global__ void kc_inv(float* dp, float* dn, int n) {
    int i = blockIdx.x * BLK + threadIdx.x;
    if (i < n) {
        float a = dp[i]; dp[i] = (a != 0.f) ? 1.f / a : 0.f;
        float b = dn[i]; dn[i] = (b != 0.f) ? 1.f / b : 0.f;
    }
}
__global__ void kc_base(float* __restrict__ out, const float* __restrict__ xp,
                        const float* __restrict__ wp, int n) {
    int tid = blockIdx.x * BLK + threadIdx.x;
    if (tid < n * 2 * D) {
        int i = tid >> 7, l = tid & 127;
        out[tid] = (l < D) ? wp[0] * xp[i * D + l] : 0.0f;
    }
}
__global__ void kc_selfinit(const float* dinv, const float* x, float* y, int nd) {
    int t = blockIdx.x * BLK + threadIdx.x;
    if (t < nd) { int i = t >> 6; y[t] = 0.5f * dinv[i] * x[t]; }
}
__global__ void kc_zero(float* y, int nd) {
    int t = blockIdx.x * BLK + threadIdx.x;
    if (t < nd) y[t] = 0.0f;
}
__global__ void kc_scatter(const int* row, const int* col, const float* w,
                           const float* dinv, const float* x, float* y, int e) {
    int t = blockIdx.x * BLK + threadIdx.x;
    int edge = t >> 6;
    if (edge < e) {
        int l = t & 63;
        int r = row[edge], c = col[edge];
        atomicAdd(&y[r * D + l], dinv[r] * w[edge] * x[c * D + l]);
    }
}
__global__ void kc_axpy(float* out, const float* src, const float* wv, int wi, int off, int nd) {
    int t = blockIdx.x * BLK + threadIdx.x;
    if (t < nd) {
        int i = t >> 6, l = t & 63;
        out[i * 2 * D + off + l] += wv[wi] * src[t];
    }
}

extern "C" void kernel_launch(void* const* d_in, const int* in_sizes, int n_in,
                              void* d_out, int out_size, void* d_ws, size_t ws_size,
                              hipStream_t stream) {
    const int*   eip = (const int*)  d_in[0];
    const float* ewp = (const float*)d_in[1];
    const int*   ein = (const int*)  d_in[2];
    const float* ewn = (const float*)d_in[3];
    const float* xp  = (const float*)d_in[4];
    const float* xn  = (const float*)d_in[5];
    const float* wp  = (const float*)d_in[6];
    const float* wn  = (const float*)d_in[7];

    const int EP = in_sizes[0] / 2;
    const int EN = in_sizes[2] / 2;
    const int n  = in_sizes[4] / D;
    const int nd = n * D;
    const int NB = cdiv(n, BROWS);

    const int* row_p = eip;
    const int* col_p = eip + EP;
    const int* row_n = ein;
    const int* col_n = ein + EN;

    float* out = (float*)d_out;

    const int gN   = cdiv(n, BLK);
    const int gEP1 = cdiv(EP, BLK);
    const int gEN1 = cdiv(EN, BLK);
    const int g16  = cdiv((long)n * 16, BLK);

    // ---- ws layout (dwords): csrp | csrn | X (buckets -> t1q,y2q) | xq | header ----
    size_t csrE = (size_t)2 * EP + (size_t)2 * EN;
    size_t Xsz  = (size_t)2 * EP + (size_t)2 * EN;          // buckets
    size_t tmpE = (size_t)nd / 2 + (size_t)nd / 2;          // t1q + y2q
    if (tmpE > Xsz) Xsz = tmpE;
    Xsz = (Xsz + 3) & ~(size_t)3;
    size_t xqE  = (size_t)nd / 2;                            // fp8 interleaved inputs
    size_t hdr  = 4 * (size_t)n + 2 + 6 * (size_t)NBMAX + 2 + 16;
    size_t need = csrE + Xsz + xqE + hdr;

    if (ws_size >= need * 4 && NB <= NBMAX && n < (1 << 24)) {
        int*  base = (int*)d_ws;
        int2* csrp = (int2*)base;
        int2* csrn = (int2*)(base + (size_t)2 * EP);
        int*  X    = base + csrE;
        int2* bucketP = (int2*)X;
        int2* bucketN = bucketP + EP;
        uint* t1q = (uint*)X;                    // n*32 dwords, rows [fp8 a1 | fp8 b1]
        uint* y2q = t1q + (size_t)nd / 2;        // n*32 dwords, rows [fp8 xn | fp8 c1]
        uint* xq  = (uint*)(X + Xsz);            // n*32 dwords, rows [fp8 xp | fp8 xn]
        int* ip = X + Xsz + xqE;
        float* dinvp = (float*)ip;  ip += n;
        float* dinvn = (float*)ip;  ip += n;
        int* rpp = ip;              ip += n + 1;
        int* rpn = ip;              ip += n + 1;
        int* bcntp = ip;            ip += NBMAX;
        int* bcntn = ip;            ip += NBMAX;
        int* bbasep = ip;           ip += NBMAX + 1;
        int* bbasen = ip;           ip += NBMAX + 1;
        int* bcurp = ip;            ip += NBMAX;
        int* bcurn = ip;

        const bool staged = (NB <= NBSZ);
        const int et  = staged ? ETILE_S : ETILE;
        const int gTP = cdiv(EP, et);
        const int gTN = cdiv(EN, et);

        // ---- bucketed build (fused P+N) + fp8 conversion ----
        k_zb<<<cdiv(NBMAX, BLK), BLK, 0, stream>>>(bcntp, bcntn);
        k_tofp8<<<g16, BLK, 0, stream>>>(xp, xn, xq, n);
        kb_count2<<<gTP + gTN, BLK_SC, 0, stream>>>(row_p, bcntp, EP,
                                                    row_n, bcntn, EN, gTP, NB, et);
        kb_scan<<<2, NBMAX, 0, stream>>>(bcntp, bbasep, bcurp, rpp,
                                         bcntn, bbasen, bcurn, rpn, NB, n, EP, EN);
        if (staged) {
            kb_scatter2s<<<gTP + gTN, BLK_SC, 0, stream>>>(row_p, col_p, ewp, bcurp, bucketP, EP,
                                                           row_n, col_n, ewn, bcurn, bucketN, EN,
                                                           gTP, NB);
        } else {
            kb_scatter2<<<gTP + gTN, BLK_SC, 0, stream>>>(row_p, col_p, ewp, bcurp, bucketP, EP,
                                                          row_n, col_n, ewn, bcurn, bucketN, EN,
                                                          gTP, NB);
        }
        kb_fill2<<<2 * NB, BLK, 0, stream>>>(bbasep, bucketP, rpp, dinvp, csrp,
                                             bbasen, bucketN, rpn, dinvn, csrn, NB, n);

        // ---- interleave setup + 3 dual gathers (t1q/y2q overwrite dead buckets) ----
        k_y2copy<<<g16, BLK, 0, stream>>>(xq, y2q, n);
        k1_pdual<<<g16, BLK, 0, stream>>>(rpp, csrp, dinvp, xp, xn, xq, wp, t1q, y2q, out, n);
        k2_ndual<<<g16, BLK, 0, stream>>>(rpn, csrn, dinvn, y2q, wn, t1q, out, n);
        k3_pdual<<<g16, BLK, 0, stream>>>(rpp, csrp, dinvp, t1q, wp, wn, out, n);
        return;
    }

    // ---------------- Tier C: atomic-scatter fallback ----------------
    float* ws    = (float*)d_ws;
    float* dinvp = ws;
    float* dinvn = ws + n;
    float* t0    = ws + 2 * n;
    float* t1    = t0 + (size_t)nd;

    const int gND  = cdiv(nd, BLK);
    const int gOUT = cdiv((long)n * 2 * D, BLK);
    const int gEPd = cdiv((long)EP * D, BLK);
    const int gENd = cdiv((long)EN * D, BLK);

    kc_init<<<gN, BLK, 0, stream>>>(dinvp, dinvn, n);
    kc_accum<<<gEP1, BLK, 0, stream>>>(row_p, ewp, dinvp, EP);
    kc_accum<<<gEN1, BLK, 0, stream>>>(row_n, ewn, dinvn, EN);
    kc_inv<<<gN, BLK, 0, stream>>>(dinvp, dinvn, n);

    kc_base<<<gOUT, BLK, 0, stream>>>(out, xp, wp, n);

    kc_selfinit<<<gND, BLK, 0, stream>>>(dinvp, xp, t0, nd);
    kc_scatter<<<gEPd, BLK, 0, stream>>>(row_p, col_p, ewp, dinvp, xp, t0, EP);
    kc_axpy<<<gND, BLK, 0, stream>>>(out, t0, wp, 1, 0, nd);

    kc_selfinit<<<gND, BLK, 0, stream>>>(dinvp, t0, t1, nd);
    kc_scatter<<<gEPd, BLK, 0, stream>>>(row_p, col_p, ewp, dinvp, t0, t1, EP);
    kc_axpy<<<gND, BLK, 0, stream>>>(out, t1, wp, 2, 0, nd);

    kc_zero<<<gND, BLK, 0, stream>>>(t1, nd);
    kc_scatter<<<gENd, BLK, 0, stream>>>(row_n, col_n, ewn, dinvn, xn, t1, EN);
    kc_axpy<<<gND, BLK, 0, stream>>>(out, t1, wn, 0, D, nd);

    kc_selfinit<<<gND, BLK, 0, stream>>>(dinvp, t1, t0, nd);
    kc_scatter<<<gEPd, BLK, 0, stream>>>(row_p, col_p, ewp, dinvp, t1, t0, EP);
    kc_axpy<<<gND, BLK, 0, stream>>>(out, t0, wn, 1, D, nd);

    kc_selfinit<<<gND, BLK, 0, stream>>>(dinvp, xn, t0, nd);
    kc_scatter<<<gEPd, BLK, 0, stream>>>(row_p, col_p, ewp, dinvp, xn, t0, EP);

    kc_zero<<<gND, BLK, 0, stream>>>(t1, nd);
    kc_scatter<<<gENd, BLK, 0, stream>>>(row_n, col_n, ewn, dinvn, t0, t1, EN);
    kc_axpy<<<gND, BLK, 0, stream>>>(out, t1, wn, 2, D, nd);
}